// Round 1
// baseline (949.406 us; speedup 1.0000x reference)
//
#include <hip/hip_runtime.h>
#include <math.h>

// Problem constants (fixed by reference)
#define B_ 2
#define S_ 2048
#define E_ 1024
#define H_ 16
#define D_ 64
#define M_ (B_ * S_)          // 4096 rows of x / attention-out
#define SCALE_ (-32.0f)       // HEAD_DIM * -0.5, multiplicative (faithful source bug)

// ============================================================================
// GEMM: C = A @ W^T   (A: [M_ x E_] row-major, W: [E_ x E_] row-major)
// permuteKV = 0: plain C[m][n] ([M_ x E_])
// permuteKV = 1: store to [B,H,S,D] layout (for K / V buffers)
// fp32 on purpose: logits are softmax-critical (scale -32 => near-one-hot,
// bf16 noise flips argmax rows => O(1) output error vs 0.119 threshold).
// ============================================================================
#define GBM 128
#define GBN 128
#define GBK 16
#define GLD 132   // LDS stride (floats) for transposed [k][m] tiles; %4==0 for b128 reads

__global__ __launch_bounds__(256, 2)
void gemm_xwt(const float* __restrict__ A, const float* __restrict__ W,
              float* __restrict__ C, const int permuteKV)
{
    __shared__ float At[GBK * GLD];
    __shared__ float Wt[GBK * GLD];

    const int tid = threadIdx.x;
    const int m0 = blockIdx.y * GBM;
    const int n0 = blockIdx.x * GBN;
    const int tx = tid & 15;
    const int ty = tid >> 4;
    const int lrow = tid >> 2;        // 0..63
    const int lc = (tid & 3) << 2;    // 0,4,8,12

    float acc[2][2][4][4];
#pragma unroll
    for (int p = 0; p < 2; ++p)
#pragma unroll
        for (int q = 0; q < 2; ++q)
#pragma unroll
            for (int i = 0; i < 4; ++i)
#pragma unroll
                for (int j = 0; j < 4; ++j)
                    acc[p][q][i][j] = 0.f;

    const float* Ap0 = A + (size_t)(m0 + lrow) * E_ + lc;
    const float* Ap1 = Ap0 + (size_t)64 * E_;
    const float* Wp0 = W + (size_t)(n0 + lrow) * E_ + lc;
    const float* Wp1 = Wp0 + (size_t)64 * E_;

    for (int k0 = 0; k0 < E_; k0 += GBK) {
        const float4 a0 = *(const float4*)(Ap0 + k0);
        const float4 a1 = *(const float4*)(Ap1 + k0);
        const float4 w0 = *(const float4*)(Wp0 + k0);
        const float4 w1 = *(const float4*)(Wp1 + k0);
        __syncthreads();   // previous iteration's reads done before overwrite
        At[(lc + 0) * GLD + lrow] = a0.x;
        At[(lc + 1) * GLD + lrow] = a0.y;
        At[(lc + 2) * GLD + lrow] = a0.z;
        At[(lc + 3) * GLD + lrow] = a0.w;
        At[(lc + 0) * GLD + 64 + lrow] = a1.x;
        At[(lc + 1) * GLD + 64 + lrow] = a1.y;
        At[(lc + 2) * GLD + 64 + lrow] = a1.z;
        At[(lc + 3) * GLD + 64 + lrow] = a1.w;
        Wt[(lc + 0) * GLD + lrow] = w0.x;
        Wt[(lc + 1) * GLD + lrow] = w0.y;
        Wt[(lc + 2) * GLD + lrow] = w0.z;
        Wt[(lc + 3) * GLD + lrow] = w0.w;
        Wt[(lc + 0) * GLD + 64 + lrow] = w1.x;
        Wt[(lc + 1) * GLD + 64 + lrow] = w1.y;
        Wt[(lc + 2) * GLD + 64 + lrow] = w1.z;
        Wt[(lc + 3) * GLD + 64 + lrow] = w1.w;
        __syncthreads();
#pragma unroll
        for (int k = 0; k < GBK; ++k) {
            const float4 aL = *(const float4*)(&At[k * GLD + (ty << 2)]);
            const float4 aH = *(const float4*)(&At[k * GLD + 64 + (ty << 2)]);
            const float4 bL = *(const float4*)(&Wt[k * GLD + (tx << 2)]);
            const float4 bH = *(const float4*)(&Wt[k * GLD + 64 + (tx << 2)]);
            const float av[2][4] = {{aL.x, aL.y, aL.z, aL.w},
                                    {aH.x, aH.y, aH.z, aH.w}};
            const float bv[2][4] = {{bL.x, bL.y, bL.z, bL.w},
                                    {bH.x, bH.y, bH.z, bH.w}};
#pragma unroll
            for (int p = 0; p < 2; ++p)
#pragma unroll
                for (int q = 0; q < 2; ++q)
#pragma unroll
                    for (int i = 0; i < 4; ++i)
#pragma unroll
                        for (int j = 0; j < 4; ++j)
                            acc[p][q][i][j] += av[p][i] * bv[q][j];
        }
    }

    // Store: rows m0 + p*64 + 4ty + i, cols n0 + q*64 + 4tx + j (j contiguous)
#pragma unroll
    for (int p = 0; p < 2; ++p)
#pragma unroll
        for (int q = 0; q < 2; ++q)
#pragma unroll
            for (int i = 0; i < 4; ++i) {
                const int m = m0 + p * 64 + (ty << 2) + i;
                const int n = n0 + q * 64 + (tx << 2);
                float4 v;
                v.x = acc[p][q][i][0];
                v.y = acc[p][q][i][1];
                v.z = acc[p][q][i][2];
                v.w = acc[p][q][i][3];
                size_t idx;
                if (!permuteKV) {
                    idx = (size_t)m * E_ + n;
                } else {
                    const int b = m >> 11;        // / S_
                    const int s = m & (S_ - 1);
                    const int h = n >> 6;         // / D_  (64-col half stays in one head)
                    const int d = n & (D_ - 1);
                    idx = ((size_t)(b * H_ + h) * S_ + s) * D_ + d;
                }
                *(float4*)(C + idx) = v;
            }
}

// ============================================================================
// Attention per (b,h): logits = K @ V^T * SCALE_, softmax rows, O = P @ V.
// One block per (bh, 64-row s-tile). Flash-style online softmax over 64-wide
// t-tiles. K^T tile resident in LDS for the whole block.
// LDS: Kt [d][s] + union(V^T [d][t] / P^T [t][s]) + Vnat [t][d] = 52 KB.
// ============================================================================
#define ALD 68

__global__ __launch_bounds__(256, 2)
void attn_kernel(const float* __restrict__ Kg, const float* __restrict__ Vg,
                 float* __restrict__ Og)
{
    __shared__ float Kt[D_ * ALD];     // [d][s] transposed K tile
    __shared__ float VtPt[D_ * ALD];   // phase A: V^T [d][t]; phase B: P^T [t][s]
    __shared__ float Vn[64 * ALD];     // [t][d] natural V tile

    const int tid = threadIdx.x;
    const int bh = blockIdx.x >> 5;    // b*H_ + h
    const int st = blockIdx.x & 31;    // s-tile index
    const int tx = tid & 15;
    const int ty = tid >> 4;
    const int lr = tid >> 2;           // 0..63 (loader row)
    const int lc = (tid & 3) << 4;     // 0,16,32,48 (loader col base)

    const float* Kp = Kg + ((size_t)bh * S_ + (size_t)st * 64) * D_;
    const float* Vp = Vg + (size_t)bh * S_ * D_;

    // Load K tile (64x64) transposed into Kt
#pragma unroll
    for (int u = 0; u < 4; ++u) {
        const float4 kv = *(const float4*)(Kp + (size_t)lr * D_ + lc + (u << 2));
        Kt[(lc + (u << 2) + 0) * ALD + lr] = kv.x;
        Kt[(lc + (u << 2) + 1) * ALD + lr] = kv.y;
        Kt[(lc + (u << 2) + 2) * ALD + lr] = kv.z;
        Kt[(lc + (u << 2) + 3) * ALD + lr] = kv.w;
    }

    float m_i[4], l_i[4], oacc[4][4];
#pragma unroll
    for (int i = 0; i < 4; ++i) {
        m_i[i] = -INFINITY;
        l_i[i] = 0.f;
#pragma unroll
        for (int j = 0; j < 4; ++j) oacc[i][j] = 0.f;
    }

    for (int t0 = 0; t0 < S_; t0 += 64) {
        __syncthreads();  // prior PV reads (and Kt writes at t0=0) complete
        // Stage V tile: natural [t][d] and transposed [d][t]
#pragma unroll
        for (int u = 0; u < 4; ++u) {
            const float4 vv = *(const float4*)(Vp + (size_t)(t0 + lr) * D_ + lc + (u << 2));
            *(float4*)(&Vn[lr * ALD + lc + (u << 2)]) = vv;
            VtPt[(lc + (u << 2) + 0) * ALD + lr] = vv.x;
            VtPt[(lc + (u << 2) + 1) * ALD + lr] = vv.y;
            VtPt[(lc + (u << 2) + 2) * ALD + lr] = vv.z;
            VtPt[(lc + (u << 2) + 3) * ALD + lr] = vv.w;
        }
        __syncthreads();

        // S tile: sc[i][j] = SCALE_ * sum_d K[s][d] * V[t][d]
        float sc[4][4];
#pragma unroll
        for (int i = 0; i < 4; ++i)
#pragma unroll
            for (int j = 0; j < 4; ++j) sc[i][j] = 0.f;
#pragma unroll 8
        for (int d = 0; d < D_; ++d) {
            const float4 kk = *(const float4*)(&Kt[d * ALD + (ty << 2)]);
            const float4 vv = *(const float4*)(&VtPt[d * ALD + (tx << 2)]);
            const float ka[4] = {kk.x, kk.y, kk.z, kk.w};
            const float va[4] = {vv.x, vv.y, vv.z, vv.w};
#pragma unroll
            for (int i = 0; i < 4; ++i)
#pragma unroll
                for (int j = 0; j < 4; ++j) sc[i][j] += ka[i] * va[j];
        }
#pragma unroll
        for (int i = 0; i < 4; ++i)
#pragma unroll
            for (int j = 0; j < 4; ++j) sc[i][j] *= SCALE_;

        // Online softmax update (row reductions across the 16 tx lanes)
#pragma unroll
        for (int i = 0; i < 4; ++i) {
            float mx = fmaxf(fmaxf(sc[i][0], sc[i][1]), fmaxf(sc[i][2], sc[i][3]));
#pragma unroll
            for (int o = 1; o < 16; o <<= 1) mx = fmaxf(mx, __shfl_xor(mx, o));
            const float nm = fmaxf(m_i[i], mx);
            const float alpha = __expf(m_i[i] - nm);  // exp(-inf)=0 on first tile
            m_i[i] = nm;
            float rs = 0.f;
#pragma unroll
            for (int j = 0; j < 4; ++j) {
                sc[i][j] = __expf(sc[i][j] - nm);
                rs += sc[i][j];
            }
#pragma unroll
            for (int o = 1; o < 16; o <<= 1) rs += __shfl_xor(rs, o);
            l_i[i] = l_i[i] * alpha + rs;
#pragma unroll
            for (int j = 0; j < 4; ++j) oacc[i][j] *= alpha;
        }

        __syncthreads();  // all threads done reading VtPt as V^T
        // Write P^T [t][s]
#pragma unroll
        for (int i = 0; i < 4; ++i)
#pragma unroll
            for (int j = 0; j < 4; ++j)
                VtPt[((tx << 2) + j) * ALD + (ty << 2) + i] = sc[i][j];
        __syncthreads();

        // O += P @ V : oacc[i][j] += sum_t P[s][t] * V[t][d]
#pragma unroll 8
        for (int t = 0; t < 64; ++t) {
            const float4 pp = *(const float4*)(&VtPt[t * ALD + (ty << 2)]);
            const float4 vv = *(const float4*)(&Vn[t * ALD + (tx << 2)]);
            const float pa[4] = {pp.x, pp.y, pp.z, pp.w};
            const float va[4] = {vv.x, vv.y, vv.z, vv.w};
#pragma unroll
            for (int i = 0; i < 4; ++i)
#pragma unroll
                for (int j = 0; j < 4; ++j) oacc[i][j] += pa[i] * va[j];
        }
    }

    // Epilogue: normalize and store to [B,S,E] layout
    const int b = bh >> 4;
    const int h = bh & 15;
#pragma unroll
    for (int i = 0; i < 4; ++i) {
        const int s = (st << 6) + (ty << 2) + i;
        const float inv = 1.f / l_i[i];
        float4 o;
        o.x = oacc[i][0] * inv;
        o.y = oacc[i][1] * inv;
        o.z = oacc[i][2] * inv;
        o.w = oacc[i][3] * inv;
        *(float4*)(Og + ((size_t)b * S_ + s) * E_ + (h << 6) + (tx << 2)) = o;
    }
}

// ============================================================================
extern "C" void kernel_launch(void* const* d_in, const int* in_sizes, int n_in,
                              void* d_out, int out_size, void* d_ws, size_t ws_size,
                              hipStream_t stream)
{
    (void)in_sizes; (void)n_in; (void)out_size; (void)ws_size;
    const float* x  = (const float*)d_in[0];
    // d_in[1] = Wq: computed-but-unused in reference; skipped entirely.
    const float* Wk = (const float*)d_in[2];
    const float* Wv = (const float*)d_in[3];
    const float* Wo = (const float*)d_in[4];
    float* out = (float*)d_out;

    // Workspace: K [B,H,S,D] (16MB) | V [B,H,S,D] (16MB) | O [B,S,E] (16MB)
    float* Kbuf = (float*)d_ws;
    float* Vbuf = Kbuf + (size_t)M_ * E_;
    float* Obuf = Vbuf + (size_t)M_ * E_;

    const dim3 gblk(256);
    const dim3 ggrid(E_ / GBN, M_ / GBM);   // (8, 32) = 256 blocks

    gemm_xwt<<<ggrid, gblk, 0, stream>>>(x, Wk, Kbuf, 1);
    gemm_xwt<<<ggrid, gblk, 0, stream>>>(x, Wv, Vbuf, 1);
    attn_kernel<<<dim3(B_ * H_ * (S_ / 64)), gblk, 0, stream>>>(Kbuf, Vbuf, Obuf);
    gemm_xwt<<<ggrid, gblk, 0, stream>>>(Obuf, Wo, out, 0);
}

// Round 3
// 340.453 us; speedup vs baseline: 2.7887x; 2.7887x over previous
//
#include <hip/hip_runtime.h>
#include <math.h>

// Problem constants (fixed by reference)
#define B_ 2
#define S_ 2048
#define E_ 1024
#define H_ 16
#define D_ 64
#define M_ (B_ * S_)          // 4096 rows
#define SCALE_ (-32.0f)       // HEAD_DIM * -0.5 (faithful source bug)

typedef __attribute__((ext_vector_type(8))) short short8;   // 8 bf16 = 4 VGPRs
typedef __attribute__((ext_vector_type(16))) float f32x16;  // 32x32 MFMA acc

static __device__ __forceinline__ unsigned short bf16_rne(float x) {
    unsigned u = __float_as_uint(x);
    u += 0x7FFFu + ((u >> 16) & 1u);   // round-to-nearest-even
    return (unsigned short)(u >> 16);
}
static __device__ __forceinline__ float bf16f(unsigned short h) {
    return __uint_as_float(((unsigned)h) << 16);
}
static __device__ __forceinline__ f32x16 mfma_b(short8 a, short8 b, f32x16 c) {
    return __builtin_amdgcn_mfma_f32_32x32x16_bf16(a, b, c, 0, 0, 0);
}
static __device__ __forceinline__ unsigned pack2(unsigned short a, unsigned short b) {
    return (unsigned)a | ((unsigned)b << 16);
}

// ============================================================================
// GEMM C = A @ W^T via 32x32x16 bf16 MFMA, fp32 inputs split hi/lo.
// npass=3: C = Ah*Wh + Ah*Wl + Al*Wh (fp32-grade; for softmax-critical K,V)
// npass=1: C = Ah*Wh (for the final @ Wo^T; ~0.4% rel err, harmless)
// MFMA form: C[m][n] = sum_k A[m][k]*B[n][k]  -> both operands natural [row][k].
// C/D: col=lane&31, row=(reg&3)+8*(reg>>2)+4*(lane>>5)   [m74/m101 verified]
// Block 512 thr = 8 waves; tile 128x128; wave = 64(m) x 32(n).
// ============================================================================
#define GK 32
#define GP 40   // LDS row stride (bf16 elems): 80B -> b128 frag reads conflict-free

__global__ __launch_bounds__(512, 2)
void gemm_mfma(const float* __restrict__ A, const float* __restrict__ W,
               float* __restrict__ C, const int npass, const int permuteKV)
{
    __shared__ unsigned short Ah[128 * GP], Al[128 * GP];
    __shared__ unsigned short Wh[128 * GP], Wl[128 * GP];

    const int tid = threadIdx.x;
    const int w   = tid >> 6;
    const int l31 = tid & 31;
    const int hh  = (tid >> 5) & 1;
    const int m0 = blockIdx.y * 128;
    const int n0 = blockIdx.x * 128;
    const int wm = (w >> 2) << 6;   // wave m-offset: 0 or 64
    const int wn = (w & 3) << 5;    // wave n-offset: 0,32,64,96

    f32x16 acc[2];
#pragma unroll
    for (int r = 0; r < 16; ++r) { acc[0][r] = 0.f; acc[1][r] = 0.f; }

    const int srow = tid >> 3;          // 0..63
    const int scol = (tid & 7) << 2;    // 0..28

    for (int k0 = 0; k0 < E_; k0 += GK) {
        __syncthreads();   // previous iter's frag reads done
#pragma unroll
        for (int u = 0; u < 2; ++u) {
            const int r = srow + (u << 6);
            const float4 av = *(const float4*)(A + (size_t)(m0 + r) * E_ + k0 + scol);
            const float4 wv = *(const float4*)(W + (size_t)(n0 + r) * E_ + k0 + scol);
            const float af[4] = {av.x, av.y, av.z, av.w};
            const float wf[4] = {wv.x, wv.y, wv.z, wv.w};
            unsigned short ah4[4], wh4[4];
#pragma unroll
            for (int i = 0; i < 4; ++i) { ah4[i] = bf16_rne(af[i]); wh4[i] = bf16_rne(wf[i]); }
            *(uint2*)&Ah[r * GP + scol] = make_uint2(pack2(ah4[0], ah4[1]), pack2(ah4[2], ah4[3]));
            *(uint2*)&Wh[r * GP + scol] = make_uint2(pack2(wh4[0], wh4[1]), pack2(wh4[2], wh4[3]));
            if (npass == 3) {
                unsigned short al4[4], wl4[4];
#pragma unroll
                for (int i = 0; i < 4; ++i) {
                    al4[i] = bf16_rne(af[i] - bf16f(ah4[i]));
                    wl4[i] = bf16_rne(wf[i] - bf16f(wh4[i]));
                }
                *(uint2*)&Al[r * GP + scol] = make_uint2(pack2(al4[0], al4[1]), pack2(al4[2], al4[3]));
                *(uint2*)&Wl[r * GP + scol] = make_uint2(pack2(wl4[0], wl4[1]), pack2(wl4[2], wl4[3]));
            }
        }
        __syncthreads();

#pragma unroll
        for (int ks = 0; ks < 2; ++ks) {
            const int kb = (ks << 4) + (hh << 3);
            short8 a_h[2];
#pragma unroll
            for (int mt = 0; mt < 2; ++mt)
                a_h[mt] = *(const short8*)&Ah[(wm + (mt << 5) + l31) * GP + kb];
            const short8 b_h = *(const short8*)&Wh[(wn + l31) * GP + kb];
            if (npass == 3) {
                short8 a_l[2];
#pragma unroll
                for (int mt = 0; mt < 2; ++mt)
                    a_l[mt] = *(const short8*)&Al[(wm + (mt << 5) + l31) * GP + kb];
                const short8 b_l = *(const short8*)&Wl[(wn + l31) * GP + kb];
#pragma unroll
                for (int mt = 0; mt < 2; ++mt) {
                    acc[mt] = mfma_b(a_h[mt], b_h, acc[mt]);
                    acc[mt] = mfma_b(a_h[mt], b_l, acc[mt]);
                    acc[mt] = mfma_b(a_l[mt], b_h, acc[mt]);
                }
            } else {
#pragma unroll
                for (int mt = 0; mt < 2; ++mt)
                    acc[mt] = mfma_b(a_h[mt], b_h, acc[mt]);
            }
        }
    }

    // Epilogue: scalar dword stores, coalesced across lanes (n = l31 consecutive)
#pragma unroll
    for (int mt = 0; mt < 2; ++mt)
#pragma unroll
        for (int r = 0; r < 16; ++r) {
            const int m = m0 + wm + (mt << 5) + (r & 3) + ((r >> 2) << 3) + (hh << 2);
            const int n = n0 + wn + l31;
            size_t idx;
            if (!permuteKV) {
                idx = (size_t)m * E_ + n;
            } else {
                const int b = m >> 11, s = m & (S_ - 1);
                const int hd = n >> 6, d = n & (D_ - 1);
                idx = ((size_t)(b * H_ + hd) * S_ + s) * D_ + d;
            }
            C[idx] = acc[mt][r];
        }
}

// ============================================================================
// Attention: logits=K@V^T*(-32), softmax over t, O=P@V. MFMA version.
// Block = 256 thr (4 waves); covers 128 s-rows; wave w owns s in [32w,32w+32).
// St computed transposed: C[m=t][n=s] -> softmax col s = lane&31 (per-lane
// state m_i/l_i). PV: C[m=s][n=d] -> accumulator ROWS are s: the alpha rescale
// must be per C-ROW, broadcast via LDS Alpha[w][s]  (R2 bug: used per-lane
// alpha -> rows with later foreign max-jumps got crushed to ~0).
// ============================================================================
#define AP 72   // LDS row stride (bf16): 144B, b64/b128-aligned

__global__ __launch_bounds__(256, 2)
void attn_mfma(const float* __restrict__ Kg, const float* __restrict__ Vg,
               float* __restrict__ Og)
{
    __shared__ unsigned short Vnh[64 * AP], Vnl[64 * AP], Vth[64 * AP];
    __shared__ unsigned short Pb[4][32 * AP];
    __shared__ float Alpha[4][32];
    __shared__ float Linv[4][32];

    const int tid = threadIdx.x;
    const int w   = tid >> 6;
    const int l31 = tid & 31;
    const int hh  = (tid >> 5) & 1;
    const int bh  = blockIdx.y;
    const int sbase = blockIdx.x * 128 + (w << 5);
    const int sg = sbase + l31;           // this lane's s (St col / softmax state)

    // K fragments: B[n=s][k=d], hi/lo, loop-invariant (4 ksteps over d=64)
    short8 kfh[4], kfl[4];
    {
        const float* Kr = Kg + ((size_t)bh * S_ + sg) * D_;
#pragma unroll
        for (int ks = 0; ks < 4; ++ks) {
            const int db = (ks << 4) + (hh << 3);
            const float4 x0 = *(const float4*)(Kr + db);
            const float4 x1 = *(const float4*)(Kr + db + 4);
            const float xs[8] = {x0.x, x0.y, x0.z, x0.w, x1.x, x1.y, x1.z, x1.w};
#pragma unroll
            for (int j = 0; j < 8; ++j) {
                const unsigned short hi = bf16_rne(xs[j]);
                kfh[ks][j] = (short)hi;
                kfl[ks][j] = (short)bf16_rne(xs[j] - bf16f(hi));
            }
        }
    }

    f32x16 oacc[2];
#pragma unroll
    for (int r = 0; r < 16; ++r) { oacc[0][r] = 0.f; oacc[1][r] = 0.f; }
    float m_i = -INFINITY, l_i = 0.f;

    const int vr = tid >> 2;          // staging t-row 0..63
    const int vc = (tid & 3) << 2;    // staging col base (+16u)
    unsigned short* P = &Pb[w][0];    // per-wave P buffer

    for (int t0 = 0; t0 < S_; t0 += 64) {
        __syncthreads();   // prior tile's Vn/Vt reads complete
        // Stage V tile 64x64: natural hi/lo + transposed hi
        const float* Vp = Vg + ((size_t)bh * S_ + t0 + vr) * D_;
#pragma unroll
        for (int u = 0; u < 4; ++u) {
            const int c = vc + (u << 4);
            const float4 vv = *(const float4*)(Vp + c);
            const float f[4] = {vv.x, vv.y, vv.z, vv.w};
            unsigned short vh[4], vl[4];
#pragma unroll
            for (int i = 0; i < 4; ++i) {
                vh[i] = bf16_rne(f[i]);
                vl[i] = bf16_rne(f[i] - bf16f(vh[i]));
            }
            *(uint2*)&Vnh[vr * AP + c] = make_uint2(pack2(vh[0], vh[1]), pack2(vh[2], vh[3]));
            *(uint2*)&Vnl[vr * AP + c] = make_uint2(pack2(vl[0], vl[1]), pack2(vl[2], vl[3]));
#pragma unroll
            for (int i = 0; i < 4; ++i) Vth[(c + i) * AP + vr] = vh[i];
        }
        __syncthreads();

        // St[t][s] = sum_d V[t][d]K[s][d], 3-pass split, then * SCALE_
        f32x16 st[2];
#pragma unroll
        for (int r = 0; r < 16; ++r) { st[0][r] = 0.f; st[1][r] = 0.f; }
#pragma unroll
        for (int ks = 0; ks < 4; ++ks) {
            const int kb = (ks << 4) + (hh << 3);
#pragma unroll
            for (int mt = 0; mt < 2; ++mt) {
                const short8 avh = *(const short8*)&Vnh[((mt << 5) + l31) * AP + kb];
                const short8 avl = *(const short8*)&Vnl[((mt << 5) + l31) * AP + kb];
                st[mt] = mfma_b(avh, kfh[ks], st[mt]);
                st[mt] = mfma_b(avh, kfl[ks], st[mt]);
                st[mt] = mfma_b(avl, kfh[ks], st[mt]);
            }
        }

        // Online softmax over t (regs + h-halves) for col s = l31
        float tmax = -INFINITY;
#pragma unroll
        for (int mt = 0; mt < 2; ++mt)
#pragma unroll
            for (int r = 0; r < 16; ++r) {
                st[mt][r] *= SCALE_;
                tmax = fmaxf(tmax, st[mt][r]);
            }
        tmax = fmaxf(tmax, __shfl_xor(tmax, 32));
        const float mnew = fmaxf(m_i, tmax);
        const float alpha = __expf(m_i - mnew);   // exp(-inf)=0 first tile
        m_i = mnew;
        float rsum = 0.f;
#pragma unroll
        for (int mt = 0; mt < 2; ++mt)
#pragma unroll
            for (int r = 0; r < 16; ++r) {
                const float p = __expf(st[mt][r] - mnew);
                st[mt][r] = p;
                rsum += p;
            }
        rsum += __shfl_xor(rsum, 32);
        l_i = l_i * alpha + rsum;

        // FIX: rescale oacc per C-ROW (row s' = 8g+4hh+r), not per-lane.
        // Broadcast alpha[s'] through per-wave LDS (hh==0 half owns s'=l31).
        if (hh == 0) Alpha[w][l31] = alpha;
#pragma unroll
        for (int g = 0; g < 4; ++g) {
            const float4 avec = *(const float4*)&Alpha[w][(g << 3) + (hh << 2)];
            const float af[4] = {avec.x, avec.y, avec.z, avec.w};
#pragma unroll
            for (int r = 0; r < 4; ++r) {
                oacc[0][(g << 2) + r] *= af[r];
                oacc[1][(g << 2) + r] *= af[r];
            }
        }

        // Write P natural [s][t] bf16 (per-wave buffer): reg quad 4g..4g+3 are
        // t = 32mt + 8g + 4hh + {0..3}  -> one b64 per (mt,g)
#pragma unroll
        for (int mt = 0; mt < 2; ++mt)
#pragma unroll
            for (int g = 0; g < 4; ++g) {
                const unsigned short p0 = bf16_rne(st[mt][4 * g + 0]);
                const unsigned short p1 = bf16_rne(st[mt][4 * g + 1]);
                const unsigned short p2 = bf16_rne(st[mt][4 * g + 2]);
                const unsigned short p3 = bf16_rne(st[mt][4 * g + 3]);
                *(uint2*)&P[l31 * AP + (mt << 5) + (g << 3) + (hh << 2)] =
                    make_uint2(pack2(p0, p1), pack2(p2, p3));
            }

        // PV: o[s][d] += sum_t P[s][t] * Vt[d][t]
#pragma unroll
        for (int ks = 0; ks < 4; ++ks) {
            const int tb = (ks << 4) + (hh << 3);
            const short8 pf = *(const short8*)&P[l31 * AP + tb];
#pragma unroll
            for (int nt = 0; nt < 2; ++nt) {
                const short8 vtf = *(const short8*)&Vth[((nt << 5) + l31) * AP + tb];
                oacc[nt] = mfma_b(pf, vtf, oacc[nt]);
            }
        }
    }

    // Epilogue: normalize by l_i per C-row (broadcast via LDS), store coalesced
    if (hh == 0) Linv[w][l31] = 1.0f / l_i;
    const int b  = bh >> 4;
    const int hd = bh & 15;
    float* Or = Og + ((size_t)b * S_ + sbase) * E_ + (hd << 6);
#pragma unroll
    for (int g = 0; g < 4; ++g) {
        const float4 iv = *(const float4*)&Linv[w][(g << 3) + (hh << 2)];
        const float invs[4] = {iv.x, iv.y, iv.z, iv.w};
#pragma unroll
        for (int nt = 0; nt < 2; ++nt)
#pragma unroll
            for (int r = 0; r < 4; ++r) {
                const int sl = (g << 3) + (hh << 2) + r;   // C row = s_local
                Or[(size_t)sl * E_ + (nt << 5) + l31] = oacc[nt][4 * g + r] * invs[r];
            }
    }
}

// ============================================================================
extern "C" void kernel_launch(void* const* d_in, const int* in_sizes, int n_in,
                              void* d_out, int out_size, void* d_ws, size_t ws_size,
                              hipStream_t stream)
{
    (void)in_sizes; (void)n_in; (void)out_size; (void)ws_size;
    const float* x  = (const float*)d_in[0];
    // d_in[1] = Wq: computed-but-unused in reference; skipped.
    const float* Wk = (const float*)d_in[2];
    const float* Wv = (const float*)d_in[3];
    const float* Wo = (const float*)d_in[4];
    float* out = (float*)d_out;

    float* Kbuf = (float*)d_ws;                  // [B,H,S,D] 16MB
    float* Vbuf = Kbuf + (size_t)M_ * E_;        // [B,H,S,D] 16MB
    float* Obuf = Vbuf + (size_t)M_ * E_;        // [B,S,E]   16MB

    const dim3 ggrid(E_ / 128, M_ / 128);        // (8, 32)
    gemm_mfma<<<ggrid, 512, 0, stream>>>(x, Wk, Kbuf, 3, 1);
    gemm_mfma<<<ggrid, 512, 0, stream>>>(x, Wv, Vbuf, 3, 1);
    attn_mfma<<<dim3(S_ / 128, B_ * H_), 256, 0, stream>>>(Kbuf, Vbuf, Obuf);
    gemm_mfma<<<ggrid, 512, 0, stream>>>(Obuf, Wo, out, 1, 0);
}

// Round 4
// 260.701 us; speedup vs baseline: 3.6417x; 1.3059x over previous
//
#include <hip/hip_runtime.h>
#include <math.h>

// Problem constants (fixed by reference)
#define B_ 2
#define S_ 2048
#define E_ 1024
#define H_ 16
#define D_ 64
#define M_ (B_ * S_)
// HEAD_DIM * -0.5 = -32 (faithful source bug), with log2 fold: K *= -32/ln2
// so softmax runs in exp2 domain (v_exp_f32 is natively 2^x).
#define SC2 (-46.166241308446828f)

typedef unsigned short u16;
typedef __attribute__((ext_vector_type(8))) short short8;   // 8 bf16 = 4 VGPRs
typedef __attribute__((ext_vector_type(16))) float f32x16;  // 32x32 MFMA acc

static __device__ __forceinline__ u16 bf16_rne(float x) {
    unsigned u = __float_as_uint(x);
    u += 0x7FFFu + ((u >> 16) & 1u);   // round-to-nearest-even
    return (u16)(u >> 16);
}
static __device__ __forceinline__ float bf16f(u16 h) {
    return __uint_as_float(((unsigned)h) << 16);
}
static __device__ __forceinline__ f32x16 mfma_b(short8 a, short8 b, f32x16 c) {
    return __builtin_amdgcn_mfma_f32_32x32x16_bf16(a, b, c, 0, 0, 0);
}
static __device__ __forceinline__ unsigned pack2(u16 a, u16 b) {
    return (unsigned)a | ((unsigned)b << 16);
}

// ============================================================================
// One-shot fp32 -> bf16 hi + bf16 lo-residual split for x, Wk, Wv, Wo.
// Removes ALL conversion VALU from GEMM/attention hot loops.
// ============================================================================
__global__ __launch_bounds__(256)
void convert_split(const float* __restrict__ x, const float* __restrict__ Wk,
                   const float* __restrict__ Wv, const float* __restrict__ Wo,
                   u16* __restrict__ Xh, u16* __restrict__ Xl,
                   u16* __restrict__ Wkh, u16* __restrict__ Wkl,
                   u16* __restrict__ Wvh, u16* __restrict__ Wvl,
                   u16* __restrict__ Woh, u16* __restrict__ Wol)
{
    const int blk = blockIdx.x;
    const float* src; u16 *dh, *dl; int base;
    if (blk < 4096)      { src = x;  dh = Xh;  dl = Xl;  base = blk; }
    else if (blk < 5120) { src = Wk; dh = Wkh; dl = Wkl; base = blk - 4096; }
    else if (blk < 6144) { src = Wv; dh = Wvh; dl = Wvl; base = blk - 5120; }
    else                 { src = Wo; dh = Woh; dl = Wol; base = blk - 6144; }
    const size_t off = ((size_t)base * 256 + threadIdx.x) * 4;
    const float4 v = *(const float4*)(src + off);
    const float f[4] = {v.x, v.y, v.z, v.w};
    u16 h4[4], l4[4];
#pragma unroll
    for (int i = 0; i < 4; ++i) {
        h4[i] = bf16_rne(f[i]);
        l4[i] = bf16_rne(f[i] - bf16f(h4[i]));
    }
    *(uint2*)(dh + off) = make_uint2(pack2(h4[0], h4[1]), pack2(h4[2], h4[3]));
    *(uint2*)(dl + off) = make_uint2(pack2(l4[0], l4[1]), pack2(l4[2], l4[3]));
}

// ============================================================================
// GEMM C = A @ W^T, 32x32x16 bf16 MFMA, bf16 hi/lo inputs.
// MODE 0: fused K+V projection (two B-weight sets share the A panel),
//         npass=3 split (Ah*Bh + Ah*Bl + Al*Bh), K pre-scaled by SC2,
//         outputs: Kh/Kl, Vh/Vl bf16 [B,H,S,D] + V-hi transposed [B,H,D,S].
// MODE 1: final O @ Wo^T, npass=1 (hi only), fp32 out [M,E].
// Block 256 thr / 4 waves; tile 64(m)x128(n); wave 32x64.
// LDS: k-chunk-major [chunk][row] with chunk stride padded (+1 unit of 16B)
// -> chunk-stride mod 32 banks = 4 -> b128 frag reads AND staging writes
// spread uniformly (<=2 lanes/bank).
// Grid (E/128, M/64) = (8,64) = 512 blocks = 2 blocks/CU.
// ============================================================================
#define CSA 520    // A chunk stride (ushorts) = (64+1)*8
#define CSB 1032   // B chunk stride = (128+1)*8

template<int MODE>
__global__ __launch_bounds__(256, 2)
void gemm_k(const u16* __restrict__ Ah, const u16* __restrict__ Al,
            const u16* __restrict__ B1h, const u16* __restrict__ B1l,
            const u16* __restrict__ B2h, const u16* __restrict__ B2l,
            u16* __restrict__ Khg, u16* __restrict__ Klg,
            u16* __restrict__ Vhg, u16* __restrict__ Vlg,
            u16* __restrict__ Vtg, float* __restrict__ Cout)
{
    __shared__ u16 sAh[4 * CSA];
    __shared__ u16 sAl[MODE == 0 ? 4 * CSA : 8];
    __shared__ u16 sB1h[4 * CSB];
    __shared__ u16 sB1l[MODE == 0 ? 4 * CSB : 8];
    __shared__ u16 sB2h[MODE == 0 ? 4 * CSB : 8];
    __shared__ u16 sB2l[MODE == 0 ? 4 * CSB : 8];

    const int tid = threadIdx.x;
    const int w   = tid >> 6;
    const int l31 = tid & 31;
    const int hh  = (tid >> 5) & 1;
    const int m0  = blockIdx.y * 64;
    const int n0  = blockIdx.x * 128;
    const int wm  = (w >> 1) << 5;   // 0 or 32
    const int wn  = (w & 1) << 6;    // 0 or 64

    f32x16 acc1[2], acc2[2];
#pragma unroll
    for (int r = 0; r < 16; ++r) {
        acc1[0][r] = 0.f; acc1[1][r] = 0.f;
        acc2[0][r] = 0.f; acc2[1][r] = 0.f;
    }

    const int ar = tid >> 2, ac = tid & 3;   // A staging unit (64 rows x 4 chunks)

    for (int k0 = 0; k0 < E_; k0 += 32) {
        __syncthreads();   // prior iter's frag reads done
        {
            const size_t ga = (size_t)(m0 + ar) * E_ + k0 + (ac << 3);
            *(short8*)&sAh[ac * CSA + ar * 8] = *(const short8*)(Ah + ga);
            if constexpr (MODE == 0)
                *(short8*)&sAl[ac * CSA + ar * 8] = *(const short8*)(Al + ga);
#pragma unroll
            for (int h2 = 0; h2 < 2; ++h2) {
                const int u = tid + (h2 << 8);
                const int br = u >> 2, bc = u & 3;
                const size_t gb = (size_t)(n0 + br) * E_ + k0 + (bc << 3);
                const int lo = bc * CSB + br * 8;
                *(short8*)&sB1h[lo] = *(const short8*)(B1h + gb);
                if constexpr (MODE == 0) {
                    *(short8*)&sB1l[lo] = *(const short8*)(B1l + gb);
                    *(short8*)&sB2h[lo] = *(const short8*)(B2h + gb);
                    *(short8*)&sB2l[lo] = *(const short8*)(B2l + gb);
                }
            }
        }
        __syncthreads();

#pragma unroll
        for (int ks = 0; ks < 2; ++ks) {
            const int ch = (ks << 1) + hh;
            const short8 a_h = *(const short8*)&sAh[ch * CSA + (wm + l31) * 8];
            short8 a_l;
            if constexpr (MODE == 0)
                a_l = *(const short8*)&sAl[ch * CSA + (wm + l31) * 8];
#pragma unroll
            for (int nt = 0; nt < 2; ++nt) {
                const int ro = ch * CSB + (wn + (nt << 5) + l31) * 8;
                const short8 b1h = *(const short8*)&sB1h[ro];
                acc1[nt] = mfma_b(a_h, b1h, acc1[nt]);
                if constexpr (MODE == 0) {
                    const short8 b1l = *(const short8*)&sB1l[ro];
                    const short8 b2h = *(const short8*)&sB2h[ro];
                    const short8 b2l = *(const short8*)&sB2l[ro];
                    acc1[nt] = mfma_b(a_h, b1l, acc1[nt]);
                    acc1[nt] = mfma_b(a_l, b1h, acc1[nt]);
                    acc2[nt] = mfma_b(a_h, b2h, acc2[nt]);
                    acc2[nt] = mfma_b(a_h, b2l, acc2[nt]);
                    acc2[nt] = mfma_b(a_l, b2h, acc2[nt]);
                }
            }
        }
    }

    // Epilogue. C/D map: col = lane&31, row = (r&3)+8*(r>>2)+4*hh  [m74/m101]
#pragma unroll
    for (int nt = 0; nt < 2; ++nt) {
        const int n = n0 + wn + (nt << 5) + l31;
        if constexpr (MODE == 1) {
#pragma unroll
            for (int r = 0; r < 16; ++r) {
                const int m = m0 + wm + (r & 3) + ((r >> 2) << 3) + (hh << 2);
                Cout[(size_t)m * E_ + n] = acc1[nt][r];
            }
        } else {
            const int hd = n >> 6, d = n & 63;
            const int b  = m0 >> 11;               // block never crosses batch
            u16 vhi[16];
#pragma unroll
            for (int r = 0; r < 16; ++r) {
                const int mrow = wm + (r & 3) + ((r >> 2) << 3) + (hh << 2);
                const int s = (m0 + mrow) & (S_ - 1);
                const size_t ib = (((size_t)(b * H_ + hd) << 11) + s) * D_ + d;
                const float kv = acc1[nt][r] * SC2;
                const u16 kh_ = bf16_rne(kv);
                Khg[ib] = kh_;
                Klg[ib] = bf16_rne(kv - bf16f(kh_));
                const float vv = acc2[nt][r];
                const u16 vh_ = bf16_rne(vv);
                vhi[r] = vh_;
                Vhg[ib] = vh_;
                Vlg[ib] = bf16_rne(vv - bf16f(vh_));
            }
            // V-hi transposed [B,H,D,S]: reg quad g = 4 consecutive s at fixed d
            const size_t vtb = ((size_t)(b * H_ + hd) * D_ + d) << 11;
#pragma unroll
            for (int g = 0; g < 4; ++g) {
                const int s0 = ((m0 + wm) & (S_ - 1)) + (g << 3) + (hh << 2);
                *(uint2*)&Vtg[vtb + s0] =
                    make_uint2(pack2(vhi[4*g], vhi[4*g+1]), pack2(vhi[4*g+2], vhi[4*g+3]));
            }
        }
    }
}

// ============================================================================
// Attention: logits2 = Ks@V^T (SC2 folded into K), softmax base-2, O = P@V.
// Block 256 thr / 4 waves; 128 s-rows; wave w owns s in [32w, 32w+32).
// St: C[m=t][n=s], A = V natural hi/lo (LDS), B = Ks hi/lo (regs, invariant)
//     -> softmax col s = lane&31 (per-lane m_i/l_i state).
// PV: C[m=s][n=d], A = P (per-wave LDS), B = V^T-hi (LDS, staged from global
//     pre-transposed [B,H,D,S] -> pure b128 copies, no in-kernel transpose).
// oacc alpha-rescale is per C-ROW via LDS broadcast (R2 lesson).
// All LDS in padded k-chunk-major (conflict-free b128).
// ============================================================================
#define CSP 264   // P chunk stride = (32+1)*8

__global__ __launch_bounds__(256, 2)
void attn_mfma(const u16* __restrict__ Kh, const u16* __restrict__ Kl,
               const u16* __restrict__ Vh, const u16* __restrict__ Vl,
               const u16* __restrict__ Vt, u16* __restrict__ Obuf)
{
    __shared__ u16 sVh[8 * CSA], sVl[8 * CSA], sVt[8 * CSA];
    __shared__ u16 sP[4][8 * CSP];
    __shared__ float Alpha[4][32], Linv[4][32];

    const int tid = threadIdx.x;
    const int w   = tid >> 6;
    const int l31 = tid & 31;
    const int hh  = (tid >> 5) & 1;
    const int bh  = blockIdx.y;
    const int sbase = blockIdx.x * 128 + (w << 5);
    const int sg = sbase + l31;

    // K fragments (pre-scaled by SC2): B[n=s][k=d], hi/lo, loop-invariant
    short8 kfh[4], kfl[4];
    {
        const size_t kb = ((size_t)bh * S_ + sg) * D_;
#pragma unroll
        for (int ks = 0; ks < 4; ++ks) {
            const int db = (ks << 4) + (hh << 3);
            kfh[ks] = *(const short8*)(Kh + kb + db);
            kfl[ks] = *(const short8*)(Kl + kb + db);
        }
    }

    f32x16 oacc[2];
#pragma unroll
    for (int r = 0; r < 16; ++r) { oacc[0][r] = 0.f; oacc[1][r] = 0.f; }
    float m_i = -INFINITY, l_i = 0.f;

    u16* P = &sP[w][0];

    for (int t0 = 0; t0 < S_; t0 += 64) {
        __syncthreads();   // prior tile's frag reads complete
        // Stage V tiles: pure b128 copies (no conversion, no transpose)
#pragma unroll
        for (int h2 = 0; h2 < 2; ++h2) {
            const int u = tid + (h2 << 8);
            const int rr = u >> 3;       // 0..63
            const int cc = u & 7;        // chunk
            const size_t gn = ((size_t)bh * S_ + t0 + rr) * D_ + (cc << 3);
            const int lo = cc * CSA + rr * 8;
            *(short8*)&sVh[lo] = *(const short8*)(Vh + gn);
            *(short8*)&sVl[lo] = *(const short8*)(Vl + gn);
            const size_t gt = ((size_t)bh * D_ + rr) * S_ + t0 + (cc << 3);
            *(short8*)&sVt[lo] = *(const short8*)(Vt + gt);
        }
        __syncthreads();

        // St[t][s] = sum_d V[t][d] * Ks[s][d]  (3-pass split)
        f32x16 st[2];
#pragma unroll
        for (int r = 0; r < 16; ++r) { st[0][r] = 0.f; st[1][r] = 0.f; }
#pragma unroll
        for (int ks = 0; ks < 4; ++ks) {
            const int ch = (ks << 1) + hh;
#pragma unroll
            for (int mt = 0; mt < 2; ++mt) {
                const int ro = ch * CSA + ((mt << 5) + l31) * 8;
                const short8 avh = *(const short8*)&sVh[ro];
                const short8 avl = *(const short8*)&sVl[ro];
                st[mt] = mfma_b(avh, kfh[ks], st[mt]);
                st[mt] = mfma_b(avh, kfl[ks], st[mt]);
                st[mt] = mfma_b(avl, kfh[ks], st[mt]);
            }
        }

        // Online softmax (base-2) over t for col s = l31
        float tmax = -INFINITY;
#pragma unroll
        for (int mt = 0; mt < 2; ++mt)
#pragma unroll
            for (int r = 0; r < 16; ++r) tmax = fmaxf(tmax, st[mt][r]);
        tmax = fmaxf(tmax, __shfl_xor(tmax, 32));
        const float mnew = fmaxf(m_i, tmax);
        const float alpha = __builtin_amdgcn_exp2f(m_i - mnew);  // first tile: 0
        m_i = mnew;
        float rsum = 0.f;
#pragma unroll
        for (int mt = 0; mt < 2; ++mt)
#pragma unroll
            for (int r = 0; r < 16; ++r) {
                const float p = __builtin_amdgcn_exp2f(st[mt][r] - mnew);
                st[mt][r] = p;
                rsum += p;
            }
        rsum += __shfl_xor(rsum, 32);
        l_i = l_i * alpha + rsum;

        // Rescale oacc per C-ROW (row s' = 8g+4hh+q), broadcast via LDS
        if (hh == 0) Alpha[w][l31] = alpha;
#pragma unroll
        for (int g = 0; g < 4; ++g) {
            const float4 av = *(const float4*)&Alpha[w][(g << 3) + (hh << 2)];
            const float af[4] = {av.x, av.y, av.z, av.w};
#pragma unroll
            for (int q = 0; q < 4; ++q) {
                oacc[0][(g << 2) + q] *= af[q];
                oacc[1][(g << 2) + q] *= af[q];
            }
        }

        // P natural [s][t] bf16, per-wave buffer. Reg quad (mt,g) = 4
        // consecutive t = mt*32+8g+4hh+{0..3} -> chunk mt*4+g, offset 4hh.
#pragma unroll
        for (int mt = 0; mt < 2; ++mt)
#pragma unroll
            for (int g = 0; g < 4; ++g) {
                const u16 p0 = bf16_rne(st[mt][4*g + 0]);
                const u16 p1 = bf16_rne(st[mt][4*g + 1]);
                const u16 p2 = bf16_rne(st[mt][4*g + 2]);
                const u16 p3 = bf16_rne(st[mt][4*g + 3]);
                *(uint2*)&P[((mt << 2) + g) * CSP + l31 * 8 + (hh << 2)] =
                    make_uint2(pack2(p0, p1), pack2(p2, p3));
            }

        // PV: o[s][d] += sum_t P[s][t] * Vt[d][t]
#pragma unroll
        for (int ks = 0; ks < 4; ++ks) {
            const int ch = (ks << 1) + hh;
            const short8 pf = *(const short8*)&P[ch * CSP + l31 * 8];
#pragma unroll
            for (int nt = 0; nt < 2; ++nt) {
                const short8 vtf = *(const short8*)&sVt[ch * CSA + ((nt << 5) + l31) * 8];
                oacc[nt] = mfma_b(pf, vtf, oacc[nt]);
            }
        }
    }

    // Epilogue: normalize per C-row, store O as bf16 [M,E] (final GEMM is
    // hi-only, so this rounding is identical to R3's staging conversion).
    if (hh == 0) Linv[w][l31] = 1.0f / l_i;
    const int b  = bh >> 4;
    const int hd = bh & 15;
    u16* Or = Obuf + ((size_t)b * S_ + sbase) * E_ + (hd << 6);
#pragma unroll
    for (int g = 0; g < 4; ++g) {
        const float4 iv = *(const float4*)&Linv[w][(g << 3) + (hh << 2)];
        const float invs[4] = {iv.x, iv.y, iv.z, iv.w};
#pragma unroll
        for (int nt = 0; nt < 2; ++nt)
#pragma unroll
            for (int q = 0; q < 4; ++q) {
                const int sl = (g << 3) + (hh << 2) + q;
                Or[(size_t)sl * E_ + (nt << 5) + l31] =
                    bf16_rne(oacc[nt][(g << 2) + q] * invs[q]);
            }
    }
}

// ============================================================================
// Workspace layout (66 MB peak; R1-R3 ran with >=48 MB used fine):
//   0M Xh | 8M Xl (later aliased by Obuf) | 16M Wkh | 18M Wkl | 20M Wvh
//   22M Wvl | 24M Woh | 26M Kh (convert's Wol-junk aliases here, K-GEMM
//   overwrites it fully) | 34M Kl | 42M Vh | 50M Vl | 58M Vt | = 66M
// ============================================================================
extern "C" void kernel_launch(void* const* d_in, const int* in_sizes, int n_in,
                              void* d_out, int out_size, void* d_ws, size_t ws_size,
                              hipStream_t stream)
{
    (void)in_sizes; (void)n_in; (void)out_size; (void)ws_size;
    const float* x  = (const float*)d_in[0];
    // d_in[1] = Wq: computed-but-unused in reference; skipped.
    const float* Wk = (const float*)d_in[2];
    const float* Wv = (const float*)d_in[3];
    const float* Wo = (const float*)d_in[4];
    float* out = (float*)d_out;

    char* ws = (char*)d_ws;
    const size_t MB = 1u << 20;
    u16* Xh  = (u16*)(ws + 0 * MB);
    u16* Xl  = (u16*)(ws + 8 * MB);
    u16* Wkh = (u16*)(ws + 16 * MB);
    u16* Wkl = (u16*)(ws + 18 * MB);
    u16* Wvh = (u16*)(ws + 20 * MB);
    u16* Wvl = (u16*)(ws + 22 * MB);
    u16* Woh = (u16*)(ws + 24 * MB);
    u16* Kh  = (u16*)(ws + 26 * MB);
    u16* Kl  = (u16*)(ws + 34 * MB);
    u16* Vh  = (u16*)(ws + 42 * MB);
    u16* Vl  = (u16*)(ws + 50 * MB);
    u16* Vt  = (u16*)(ws + 58 * MB);
    u16* Obuf = Xl;        // x-lo dead after KV GEMM; attention runs after
    u16* Wol_junk = Kh;    // fully overwritten by KV GEMM before any read

    convert_split<<<7168, 256, 0, stream>>>(x, Wk, Wv, Wo,
                                            Xh, Xl, Wkh, Wkl, Wvh, Wvl, Woh, Wol_junk);
    gemm_k<0><<<dim3(E_ / 128, M_ / 64), 256, 0, stream>>>(
        Xh, Xl, Wkh, Wkl, Wvh, Wvl, Kh, Kl, Vh, Vl, Vt, nullptr);
    attn_mfma<<<dim3(S_ / 128, B_ * H_), 256, 0, stream>>>(Kh, Kl, Vh, Vl, Vt, Obuf);
    gemm_k<1><<<dim3(E_ / 128, M_ / 64), 256, 0, stream>>>(
        Obuf, Obuf, Woh, Woh, Woh, Woh,
        nullptr, nullptr, nullptr, nullptr, nullptr, out);
}

// Round 5
// 226.888 us; speedup vs baseline: 4.1845x; 1.1490x over previous
//
#include <hip/hip_runtime.h>
#include <math.h>

// Problem constants (fixed by reference)
#define B_ 2
#define S_ 2048
#define E_ 1024
#define H_ 16
#define D_ 64
#define M_ (B_ * S_)
// HEAD_DIM * -0.5 = -32 (faithful source bug), folded with 1/ln2 so the
// softmax runs in exp2 domain. Folded into Wk at convert time.
#define SC2 (-46.166241308446828f)

typedef unsigned short u16;
typedef __attribute__((ext_vector_type(8))) short short8;   // 8 bf16 = 4 VGPRs
typedef __attribute__((ext_vector_type(16))) float f32x16;  // 32x32 MFMA acc

static __device__ __forceinline__ u16 bf16_rne(float x) {
    unsigned u = __float_as_uint(x);
    u += 0x7FFFu + ((u >> 16) & 1u);
    return (u16)(u >> 16);
}
static __device__ __forceinline__ float bf16f(u16 h) {
    return __uint_as_float(((unsigned)h) << 16);
}
static __device__ __forceinline__ f32x16 mfma_b(short8 a, short8 b, f32x16 c) {
    return __builtin_amdgcn_mfma_f32_32x32x16_bf16(a, b, c, 0, 0, 0);
}
static __device__ __forceinline__ unsigned pack2(u16 a, u16 b) {
    return (unsigned)a | ((unsigned)b << 16);
}
// Truncating bf16x2 pack: out = {hi16(a), hi16(b)} in one v_perm_b32.
// (P in [0,1]; trunc bias ~2^-9 relative, harmless vs 0.119 threshold.)
static __device__ __forceinline__ unsigned pack_trunc(float a, float b) {
    return __builtin_amdgcn_perm(__float_as_uint(b), __float_as_uint(a), 0x07060302u);
}
#define ROWMAP(r, hh) (((r) & 3) + ((((r) >> 2)) << 3) + ((hh) << 2))

// ============================================================================
// One-shot fp32 -> bf16 hi + lo-residual split. SC2 folded into Wk here.
// ============================================================================
__global__ __launch_bounds__(256)
void convert_split(const float* __restrict__ x, const float* __restrict__ Wk,
                   const float* __restrict__ Wv, const float* __restrict__ Wo,
                   u16* __restrict__ Xh, u16* __restrict__ Xl,
                   u16* __restrict__ Wkh, u16* __restrict__ Wkl,
                   u16* __restrict__ Wvh, u16* __restrict__ Wvl,
                   u16* __restrict__ Woh, u16* __restrict__ Wol)
{
    const int blk = blockIdx.x;
    const float* src; u16 *dh, *dl; int base; float sc = 1.0f;
    if (blk < 4096)      { src = x;  dh = Xh;  dl = Xl;  base = blk; }
    else if (blk < 5120) { src = Wk; dh = Wkh; dl = Wkl; base = blk - 4096; sc = SC2; }
    else if (blk < 6144) { src = Wv; dh = Wvh; dl = Wvl; base = blk - 5120; }
    else                 { src = Wo; dh = Woh; dl = Wol; base = blk - 6144; }
    const size_t off = ((size_t)base * 256 + threadIdx.x) * 4;
    const float4 v = *(const float4*)(src + off);
    const float f[4] = {v.x * sc, v.y * sc, v.z * sc, v.w * sc};
    u16 h4[4], l4[4];
#pragma unroll
    for (int i = 0; i < 4; ++i) {
        h4[i] = bf16_rne(f[i]);
        l4[i] = bf16_rne(f[i] - bf16f(h4[i]));
    }
    *(uint2*)(dh + off) = make_uint2(pack2(h4[0], h4[1]), pack2(h4[2], h4[3]));
    *(uint2*)(dl + off) = make_uint2(pack2(l4[0], l4[1]), pack2(l4[2], l4[3]));
}

// ============================================================================
// GEMM C = A @ W^T, 32x32x16 bf16 MFMA, hi/lo bf16 inputs.
// MODE 0: fused K+V projection, 3-pass split each; outputs Kh/Kl/Vh/Vl
//         [B,H,S,D] bf16 + V-hi transposed [B,H,D,S]. (SC2 pre-folded in Wk.)
// MODE 1: O @ Wo^T, hi-only, fp32 out [M,E].
// 512 thr / 8 waves: wave-tile 64m x 64n computing BOTH weights (operand
// reuse R=4 -> MFMA-bound), waves K-SPLIT (ws=w>>2 takes k-half), fp32 merge
// through LDS at epilogue. Register-prefetch of tile k+1 during compute on k.
// k-chunk-major LDS, chunk stride (128+1)*8 u16 -> conflict-free b128.
// Grid (E/128, M/128) = (8,32) = 256 blocks = 1/CU, 2 waves/SIMD.
// ============================================================================
#define CSB 1032            // (128+1)*8 u16
#define ARR (4 * CSB)       // one staged array (4 k-chunks): 4128 u16

template<int MODE>
__global__ __launch_bounds__(512, 2)
void gemm_k(const u16* __restrict__ Ah, const u16* __restrict__ Al,
            const u16* __restrict__ B1h, const u16* __restrict__ B1l,
            const u16* __restrict__ B2h, const u16* __restrict__ B2l,
            u16* __restrict__ Khg, u16* __restrict__ Klg,
            u16* __restrict__ Vhg, u16* __restrict__ Vlg,
            u16* __restrict__ Vtg, float* __restrict__ Cout)
{
    __shared__ u16 stage[(MODE == 0 ? 6 : 4) * ARR];  // MODE1 keeps >=32KB for red

    const int tid = threadIdx.x;
    const int w = tid >> 6, l31 = tid & 31, hh = (tid >> 5) & 1;
    const int wt = w & 3, ws = w >> 2;          // wt: tile quadrant; ws: k-half
    const int wm = (wt >> 1) << 6, wn = (wt & 1) << 6;
    const int m0 = blockIdx.y * 128, n0 = blockIdx.x * 128;
    const int ch = (ws << 1) + hh;              // this wave's k-chunk (0..3)

    const int srow = tid >> 2;                  // staging row 0..127
    const int sch  = tid & 3;                   // staging chunk
    const size_t gA = (size_t)(m0 + srow) * E_ + (sch << 3);
    const size_t gB = (size_t)(n0 + srow) * E_ + (sch << 3);
    const int slo = sch * CSB + srow * 8;

    f32x16 acc1[2][2], acc2[2][2];
#pragma unroll
    for (int mt = 0; mt < 2; ++mt)
#pragma unroll
        for (int nt = 0; nt < 2; ++nt)
#pragma unroll
            for (int r = 0; r < 16; ++r) {
                acc1[mt][nt][r] = 0.f;
                if constexpr (MODE == 0) acc2[mt][nt][r] = 0.f;
            }

    short8 pf[6];
    auto load_tile = [&](int k0) {
        pf[0] = *(const short8*)(Ah + gA + k0);
        pf[2] = *(const short8*)(B1h + gB + k0);
        if constexpr (MODE == 0) {
            pf[1] = *(const short8*)(Al + gA + k0);
            pf[3] = *(const short8*)(B1l + gB + k0);
            pf[4] = *(const short8*)(B2h + gB + k0);
            pf[5] = *(const short8*)(B2l + gB + k0);
        }
    };
    auto store_tile = [&]() {
        *(short8*)&stage[0 * ARR + slo] = pf[0];
        *(short8*)&stage[2 * ARR + slo] = pf[2];
        if constexpr (MODE == 0) {
            *(short8*)&stage[1 * ARR + slo] = pf[1];
            *(short8*)&stage[3 * ARR + slo] = pf[3];
            *(short8*)&stage[4 * ARR + slo] = pf[4];
            *(short8*)&stage[5 * ARR + slo] = pf[5];
        }
    };

    load_tile(0);
    for (int it = 0; it < 32; ++it) {
        store_tile();
        __syncthreads();
        if (it + 1 < 32) load_tile((it + 1) << 5);   // prefetch, hidden by compute

        const int aoff = ch * CSB;
        short8 a_h[2], a_l[2];
        a_h[0] = *(const short8*)&stage[0 * ARR + aoff + (wm + l31) * 8];
        a_h[1] = *(const short8*)&stage[0 * ARR + aoff + (wm + 32 + l31) * 8];
        if constexpr (MODE == 0) {
            a_l[0] = *(const short8*)&stage[1 * ARR + aoff + (wm + l31) * 8];
            a_l[1] = *(const short8*)&stage[1 * ARR + aoff + (wm + 32 + l31) * 8];
        }
#pragma unroll
        for (int nt = 0; nt < 2; ++nt) {
            const int ro = aoff + (wn + (nt << 5) + l31) * 8;
            const short8 b1h = *(const short8*)&stage[2 * ARR + ro];
            if constexpr (MODE == 0) {
                const short8 b1l = *(const short8*)&stage[3 * ARR + ro];
                const short8 b2h = *(const short8*)&stage[4 * ARR + ro];
                const short8 b2l = *(const short8*)&stage[5 * ARR + ro];
#pragma unroll
                for (int mt = 0; mt < 2; ++mt) {
                    acc1[mt][nt] = mfma_b(a_h[mt], b1h, acc1[mt][nt]);
                    acc1[mt][nt] = mfma_b(a_h[mt], b1l, acc1[mt][nt]);
                    acc1[mt][nt] = mfma_b(a_l[mt], b1h, acc1[mt][nt]);
                    acc2[mt][nt] = mfma_b(a_h[mt], b2h, acc2[mt][nt]);
                    acc2[mt][nt] = mfma_b(a_h[mt], b2l, acc2[mt][nt]);
                    acc2[mt][nt] = mfma_b(a_l[mt], b2h, acc2[mt][nt]);
                }
            } else {
#pragma unroll
                for (int mt = 0; mt < 2; ++mt)
                    acc1[mt][nt] = mfma_b(a_h[mt], b1h, acc1[mt][nt]);
            }
        }
        __syncthreads();   // all reads done before next store_tile overwrites
    }

    // K-split merge: ws1 writes partials through LDS (fp32), ws0 accumulates.
    // 32KB scratch per round (4 wave-quadrants x 32 rows x 64 cols).
    float* red = (float*)stage;
    auto merge = [&](f32x16 (&acc)[2][2]) {
#pragma unroll
        for (int mt = 0; mt < 2; ++mt) {
            __syncthreads();
            if (ws == 1) {
#pragma unroll
                for (int nt = 0; nt < 2; ++nt)
#pragma unroll
                    for (int r = 0; r < 16; ++r)
                        red[wt * 2048 + ROWMAP(r, hh) * 64 + (nt << 5) + l31] = acc[mt][nt][r];
            }
            __syncthreads();
            if (ws == 0) {
#pragma unroll
                for (int nt = 0; nt < 2; ++nt)
#pragma unroll
                    for (int r = 0; r < 16; ++r)
                        acc[mt][nt][r] += red[wt * 2048 + ROWMAP(r, hh) * 64 + (nt << 5) + l31];
            }
        }
    };
    merge(acc1);
    if constexpr (MODE == 0) merge(acc2);

    if (ws != 0) return;

    // Epilogue stores (ws0 waves). C/D map: col=lane&31, row=ROWMAP [m74/m101]
#pragma unroll
    for (int nt = 0; nt < 2; ++nt) {
        const int n = n0 + wn + (nt << 5) + l31;
        if constexpr (MODE == 1) {
#pragma unroll
            for (int mt = 0; mt < 2; ++mt)
#pragma unroll
                for (int r = 0; r < 16; ++r) {
                    const int m = m0 + wm + (mt << 5) + ROWMAP(r, hh);
                    Cout[(size_t)m * E_ + n] = acc1[mt][nt][r];
                }
        } else {
            const int hd = n >> 6, d = n & 63;
            const int b = m0 >> 11;            // block never crosses batch
#pragma unroll
            for (int mt = 0; mt < 2; ++mt) {
                u16 vhi[16];
#pragma unroll
                for (int r = 0; r < 16; ++r) {
                    const int s = (m0 + wm + (mt << 5) + ROWMAP(r, hh)) & (S_ - 1);
                    const size_t ib = (((size_t)(b * H_ + hd) << 11) + s) * D_ + d;
                    const float kv = acc1[mt][nt][r];      // SC2 already folded
                    const u16 kh_ = bf16_rne(kv);
                    Khg[ib] = kh_;
                    Klg[ib] = bf16_rne(kv - bf16f(kh_));
                    const float vv = acc2[mt][nt][r];
                    const u16 vh_ = bf16_rne(vv);
                    vhi[r] = vh_;
                    Vhg[ib] = vh_;
                    Vlg[ib] = bf16_rne(vv - bf16f(vh_));
                }
                const size_t vtb = ((size_t)(b * H_ + hd) * D_ + d) << 11;
#pragma unroll
                for (int g = 0; g < 4; ++g) {
                    const int s0 = ((m0 + wm + (mt << 5)) & (S_ - 1)) + (g << 3) + (hh << 2);
                    *(uint2*)&Vtg[vtb + s0] =
                        make_uint2(pack2(vhi[4 * g], vhi[4 * g + 1]),
                                   pack2(vhi[4 * g + 2], vhi[4 * g + 3]));
                }
            }
        }
    }
}

// ============================================================================
// Attention: logits2 = Ks@V^T, base-2 online softmax, O = P@V.
// 512 thr / 8 waves; 256 s-rows/block; wave w owns s in [32w,32w+32).
// St: C[m=t][n=s] (A=V hi/lo LDS, B=Ks hi/lo regs) -> per-lane softmax state.
// PV: C[m=s][n=d] (A=P per-wave LDS, B=V^T-hi pre-transposed in global).
// Ballot-skips: alpha rescale when max unmoved; whole P+PV when tile is
// >2^-30 below running max (near-one-hot logits -> many dead tiles).
// Register-prefetch of next V tile during compute.
// ============================================================================
#define CSA 520             // (64+1)*8 u16
#define VA  (8 * CSA)       // one V array: 4160 u16
#define CSP 264             // (32+1)*8 u16
#define PW  (8 * CSP)       // per-wave P: 2112 u16

__global__ __launch_bounds__(512, 2)
void attn_mfma(const u16* __restrict__ Kh, const u16* __restrict__ Kl,
               const u16* __restrict__ Vh, const u16* __restrict__ Vl,
               const u16* __restrict__ Vt, u16* __restrict__ Obuf)
{
    __shared__ u16 sV[3 * VA];          // [Vh | Vl | Vt]
    __shared__ u16 sP[8][PW];
    __shared__ float Alpha[8][32], Linv[8][32];

    const int tid = threadIdx.x;
    const int w = tid >> 6, l31 = tid & 31, hh = (tid >> 5) & 1;
    const int bh = blockIdx.y;
    const int sbase = blockIdx.x * 256 + (w << 5);
    const int sg = sbase + l31;

    // K fragments (SC2 pre-folded): B[n=s][k=d], hi/lo, loop-invariant
    short8 kfh[4], kfl[4];
    {
        const size_t kb = ((size_t)bh * S_ + sg) * D_;
#pragma unroll
        for (int ks = 0; ks < 4; ++ks) {
            const int db = (ks << 4) + (hh << 3);
            kfh[ks] = *(const short8*)(Kh + kb + db);
            kfl[ks] = *(const short8*)(Kl + kb + db);
        }
    }

    f32x16 oacc[2];
#pragma unroll
    for (int r = 0; r < 16; ++r) { oacc[0][r] = 0.f; oacc[1][r] = 0.f; }
    float m_i = -INFINITY, l_i = 0.f;

    const int rr = tid >> 3, cc = tid & 7;     // staging: row 0..63, chunk 0..7
    const size_t gn = ((size_t)bh * S_ + rr) * D_ + (cc << 3);
    const size_t gt = ((size_t)bh * D_ + rr) * S_ + (cc << 3);
    const int slo = cc * CSA + rr * 8;
    u16* P = &sP[w][0];

    short8 pv[3];
    auto load_tile = [&](int t0) {
        pv[0] = *(const short8*)(Vh + gn + (size_t)t0 * D_);
        pv[1] = *(const short8*)(Vl + gn + (size_t)t0 * D_);
        pv[2] = *(const short8*)(Vt + gt + t0);
    };

    load_tile(0);
    for (int it = 0; it < 32; ++it) {
        *(short8*)&sV[slo] = pv[0];
        *(short8*)&sV[VA + slo] = pv[1];
        *(short8*)&sV[2 * VA + slo] = pv[2];
        __syncthreads();
        if (it + 1 < 32) load_tile((it + 1) << 6);   // prefetch

        // St[t][s] = sum_d V[t][d] * Ks[s][d]  (3-pass split)
        f32x16 st[2];
#pragma unroll
        for (int r = 0; r < 16; ++r) { st[0][r] = 0.f; st[1][r] = 0.f; }
#pragma unroll
        for (int ks = 0; ks < 4; ++ks) {
            const int ch = (ks << 1) + hh;
#pragma unroll
            for (int mt = 0; mt < 2; ++mt) {
                const int ro = ch * CSA + ((mt << 5) + l31) * 8;
                const short8 avh = *(const short8*)&sV[ro];
                const short8 avl = *(const short8*)&sV[VA + ro];
                st[mt] = mfma_b(avh, kfh[ks], st[mt]);
                st[mt] = mfma_b(avh, kfl[ks], st[mt]);
                st[mt] = mfma_b(avl, kfh[ks], st[mt]);
            }
        }

        // Online softmax over t for col s = l31 (base 2)
        float tmax = -INFINITY;
#pragma unroll
        for (int mt = 0; mt < 2; ++mt)
#pragma unroll
            for (int r = 0; r < 16; ++r) tmax = fmaxf(tmax, st[mt][r]);
        tmax = fmaxf(tmax, __shfl_xor(tmax, 32));
        const float mnew = fmaxf(m_i, tmax);
        const float alpha = __builtin_amdgcn_exp2f(m_i - mnew);  // first tile: 0
        m_i = mnew;
        // tile contributes only if within 2^-30 of this row's running max
        const unsigned long long cmask = __ballot(tmax >= mnew - 30.f);

        if (cmask) {
            float rsum = 0.f;
#pragma unroll
            for (int mt = 0; mt < 2; ++mt)
#pragma unroll
                for (int r = 0; r < 16; ++r) {
                    const float p = __builtin_amdgcn_exp2f(st[mt][r] - mnew);
                    st[mt][r] = p;
                    rsum += p;
                }
            rsum += __shfl_xor(rsum, 32);
            l_i = l_i * alpha + rsum;
        }
        // Rescale oacc per C-ROW (row s' = 8g+4hh+q) only if any max moved
        if (__ballot(alpha != 1.0f)) {
            if (hh == 0) Alpha[w][l31] = alpha;
#pragma unroll
            for (int g = 0; g < 4; ++g) {
                const float4 av = *(const float4*)&Alpha[w][(g << 3) + (hh << 2)];
                const float af[4] = {av.x, av.y, av.z, av.w};
#pragma unroll
                for (int q = 0; q < 4; ++q) {
                    oacc[0][(g << 2) + q] *= af[q];
                    oacc[1][(g << 2) + q] *= af[q];
                }
            }
        }
        if (cmask) {
            // P natural [s][t]: reg quad (mt,g) = t = 32mt+8g+4hh+{0..3}
#pragma unroll
            for (int mt = 0; mt < 2; ++mt)
#pragma unroll
                for (int g = 0; g < 4; ++g)
                    *(uint2*)&P[((mt << 2) + g) * CSP + l31 * 8 + (hh << 2)] =
                        make_uint2(pack_trunc(st[mt][4 * g], st[mt][4 * g + 1]),
                                   pack_trunc(st[mt][4 * g + 2], st[mt][4 * g + 3]));
            // PV: o[s][d] += sum_t P[s][t] * Vt[d][t]
#pragma unroll
            for (int ks = 0; ks < 4; ++ks) {
                const int ch = (ks << 1) + hh;
                const short8 pfr = *(const short8*)&P[ch * CSP + l31 * 8];
#pragma unroll
                for (int nt = 0; nt < 2; ++nt) {
                    const short8 vtf = *(const short8*)&sV[2 * VA + ch * CSA + ((nt << 5) + l31) * 8];
                    oacc[nt] = mfma_b(pfr, vtf, oacc[nt]);
                }
            }
        }
        __syncthreads();   // all reads done before next tile overwrites sV
    }

    // Epilogue: normalize per C-row, store bf16 [M,E]
    if (hh == 0) Linv[w][l31] = 1.0f / l_i;
    const int b = bh >> 4;
    const int hd = bh & 15;
    u16* Or = Obuf + ((size_t)b * S_ + sbase) * E_ + (hd << 6);
#pragma unroll
    for (int g = 0; g < 4; ++g) {
        const float4 iv = *(const float4*)&Linv[w][(g << 3) + (hh << 2)];
        const float invs[4] = {iv.x, iv.y, iv.z, iv.w};
#pragma unroll
        for (int nt = 0; nt < 2; ++nt)
#pragma unroll
            for (int q = 0; q < 4; ++q) {
                const int sl = (g << 3) + (hh << 2) + q;
                Or[(size_t)sl * E_ + (nt << 5) + l31] =
                    bf16_rne(oacc[nt][(g << 2) + q] * invs[q]);
            }
    }
}

// ============================================================================
// Workspace (66 MB, same as R4):
//   0M Xh | 8M Xl (aliased by Obuf after gemm0) | 16M Wkh | 18M Wkl | 20M Wvh
//   22M Wvl | 24M Woh | 26M Kh (convert's Wol-junk; overwritten by gemm0)
//   34M Kl | 42M Vh | 50M Vl | 58M Vt
// ============================================================================
extern "C" void kernel_launch(void* const* d_in, const int* in_sizes, int n_in,
                              void* d_out, int out_size, void* d_ws, size_t ws_size,
                              hipStream_t stream)
{
    (void)in_sizes; (void)n_in; (void)out_size; (void)ws_size;
    const float* x  = (const float*)d_in[0];
    // d_in[1] = Wq: computed-but-unused in reference; skipped.
    const float* Wk = (const float*)d_in[2];
    const float* Wv = (const float*)d_in[3];
    const float* Wo = (const float*)d_in[4];
    float* out = (float*)d_out;

    char* ws = (char*)d_ws;
    const size_t MB = 1u << 20;
    u16* Xh  = (u16*)(ws + 0 * MB);
    u16* Xl  = (u16*)(ws + 8 * MB);
    u16* Wkh = (u16*)(ws + 16 * MB);
    u16* Wkl = (u16*)(ws + 18 * MB);
    u16* Wvh = (u16*)(ws + 20 * MB);
    u16* Wvl = (u16*)(ws + 22 * MB);
    u16* Woh = (u16*)(ws + 24 * MB);
    u16* Kh  = (u16*)(ws + 26 * MB);
    u16* Kl  = (u16*)(ws + 34 * MB);
    u16* Vh  = (u16*)(ws + 42 * MB);
    u16* Vl  = (u16*)(ws + 50 * MB);
    u16* Vt  = (u16*)(ws + 58 * MB);
    u16* Obuf = Xl;        // x-lo dead after gemm0
    u16* Wol_junk = Kh;    // fully overwritten by gemm0 before any read

    convert_split<<<7168, 256, 0, stream>>>(x, Wk, Wv, Wo,
                                            Xh, Xl, Wkh, Wkl, Wvh, Wvl, Woh, Wol_junk);
    gemm_k<0><<<dim3(E_ / 128, M_ / 128), 512, 0, stream>>>(
        Xh, Xl, Wkh, Wkl, Wvh, Wvl, Kh, Kl, Vh, Vl, Vt, nullptr);
    attn_mfma<<<dim3(S_ / 256, B_ * H_), 512, 0, stream>>>(Kh, Kl, Vh, Vl, Vt, Obuf);
    gemm_k<1><<<dim3(E_ / 128, M_ / 128), 512, 0, stream>>>(
        Obuf, Obuf, Woh, Woh, Woh, Woh,
        nullptr, nullptr, nullptr, nullptr, nullptr, out);
}